// Round 3
// baseline (170.465 us; speedup 1.0000x reference)
//
#include <hip/hip_runtime.h>
#include <stdint.h>
#include <stddef.h>

typedef __attribute__((ext_vector_type(8))) short bf16x8;
typedef __attribute__((ext_vector_type(4))) float f32x4;

#define NROWS 400000
#define KC 128
#define DIMS 64
#define NTILES (NROWS / 16)

__device__ __forceinline__ short f2bf(float f) {
    union { float f; uint32_t u; } v; v.f = f;
    uint32_t u = v.u;
    uint32_t r = (u + 0x7FFFu + ((u >> 16) & 1u)) >> 16;  // RNE, finite inputs
    return (short)r;
}

__device__ __forceinline__ float frcp(float x) { return __builtin_amdgcn_rcpf(x); }

// Stage center bf16 fragments into LDS (wave 0), cnorm in regs (norm of center cb*16+m).
__device__ __forceinline__ void stage_centers(
        const float* __restrict__ centers, bf16x8 (*blds)[2][64],
        float* cnorm, int wid, int lane, int m, int g)
{
    #pragma unroll
    for (int cb = 0; cb < 8; ++cb) {
        float cacc = 0.f;
        bf16x8 bfr[2];
        #pragma unroll
        for (int h = 0; h < 2; ++h) {
            const float* src = centers + (size_t)(cb * 16 + m) * DIMS + h * 32 + g * 8;
            f32x4 c0 = *(const f32x4*)src;
            f32x4 c1 = *(const f32x4*)(src + 4);
            bf16x8 b;
            #pragma unroll
            for (int j = 0; j < 4; ++j) {
                float f0 = c0[j], f1 = c1[j];
                cacc += f0 * f0 + f1 * f1;
                b[j]     = f2bf(f0);
                b[j + 4] = f2bf(f1);
            }
            bfr[h] = b;
        }
        cacc += __shfl_xor(cacc, 16);
        cacc += __shfl_xor(cacc, 32);
        cnorm[cb] = cacc;
        if (wid == 0) { blds[cb][0][lane] = bfr[0]; blds[cb][1][lane] = bfr[1]; }
    }
    __syncthreads();
}

// K1: column sums of q. Reads embeds only; partials written TRANSPOSED [k][block].
__global__ __launch_bounds__(256, 4) void k1_colsum(
        const float* __restrict__ embeds, const float* __restrict__ centers,
        float* __restrict__ colsum_part, int nblocks)
{
    __shared__ bf16x8 blds[8][2][64];
    __shared__ float cl[4 * 128];
    const int tid = threadIdx.x, wid = tid >> 6, lane = tid & 63;
    const int m = lane & 15, g = lane >> 4;

    float cnorm[8];
    stage_centers(centers, blds, cnorm, wid, lane, m, g);

    float csum[8];
    #pragma unroll
    for (int cb = 0; cb < 8; ++cb) csum[cb] = 0.f;

    const int gwid = blockIdx.x * 4 + wid;
    const int nw = nblocks * 4;

    int t = gwid;
    f32x4 n0, n1, n2, n3;
    if (t < NTILES) {
        const float* src = embeds + (size_t)(t * 16 + m) * DIMS + g * 8;
        n0 = *(const f32x4*)src;       n1 = *(const f32x4*)(src + 4);
        n2 = *(const f32x4*)(src + 32); n3 = *(const f32x4*)(src + 36);
    }
    for (; t < NTILES; t += nw) {
        f32x4 c0 = n0, c1 = n1, c2 = n2, c3 = n3;
        int tn = t + nw;
        if (tn < NTILES) {
            const float* src = embeds + (size_t)(tn * 16 + m) * DIMS + g * 8;
            n0 = *(const f32x4*)src;       n1 = *(const f32x4*)(src + 4);
            n2 = *(const f32x4*)(src + 32); n3 = *(const f32x4*)(src + 36);
        }
        bf16x8 a0, a1;
        float en = 0.f;
        #pragma unroll
        for (int j = 0; j < 4; ++j) {
            float f0 = c0[j], f1 = c1[j], f2 = c2[j], f3 = c3[j];
            en += f0 * f0 + f1 * f1 + f2 * f2 + f3 * f3;
            a0[j] = f2bf(f0); a0[j + 4] = f2bf(f1);
            a1[j] = f2bf(f2); a1[j + 4] = f2bf(f3);
        }
        en += __shfl_xor(en, 16);
        en += __shfl_xor(en, 32);
        float er[4];
        #pragma unroll
        for (int r = 0; r < 4; ++r) er[r] = __shfl(en, g * 4 + r);

        f32x4 acc[8];
        #pragma unroll
        for (int cb = 0; cb < 8; ++cb) {
            bf16x8 b0 = blds[cb][0][lane];
            bf16x8 b1 = blds[cb][1][lane];
            f32x4 a = {0.f, 0.f, 0.f, 0.f};
            a = __builtin_amdgcn_mfma_f32_16x16x32_bf16(a0, b0, a, 0, 0, 0);
            a = __builtin_amdgcn_mfma_f32_16x16x32_bf16(a1, b1, a, 0, 0, 0);
            acc[cb] = a;
        }

        float rs[4] = {0.f, 0.f, 0.f, 0.f};
        #pragma unroll
        for (int cb = 0; cb < 8; ++cb) {
            #pragma unroll
            for (int r = 0; r < 4; ++r) {
                float sq = fmaxf(er[r] + cnorm[cb] - 2.0f * acc[cb][r], 0.f);
                float dist = frcp(1.0f + sq);
                acc[cb][r] = dist;
                rs[r] += dist;
            }
        }
        #pragma unroll
        for (int r = 0; r < 4; ++r) {
            rs[r] += __shfl_xor(rs[r], 1);
            rs[r] += __shfl_xor(rs[r], 2);
            rs[r] += __shfl_xor(rs[r], 4);
            rs[r] += __shfl_xor(rs[r], 8);
            rs[r] = frcp(rs[r]);
        }
        #pragma unroll
        for (int cb = 0; cb < 8; ++cb) {
            #pragma unroll
            for (int r = 0; r < 4; ++r) csum[cb] += acc[cb][r] * rs[r];
        }
    }

    #pragma unroll
    for (int cb = 0; cb < 8; ++cb) {
        csum[cb] += __shfl_xor(csum[cb], 16);
        csum[cb] += __shfl_xor(csum[cb], 32);
    }
    if (lane < 16) {
        #pragma unroll
        for (int cb = 0; cb < 8; ++cb) cl[wid * 128 + cb * 16 + lane] = csum[cb];
    }
    __syncthreads();
    if (tid < 128) {
        float s = cl[tid] + cl[128 + tid] + cl[256 + tid] + cl[384 + tid];
        colsum_part[(size_t)tid * nblocks + blockIdx.x] = s;   // transposed
    }
}

// K1b: 128 blocks, block k reduces contiguous row k -> invS[k], log2S[k]
__global__ __launch_bounds__(256) void k1b_reduce(
        const float* __restrict__ part, float* __restrict__ invS,
        float* __restrict__ lS, int nb)
{
    __shared__ float lds[4];
    const int k = blockIdx.x;
    const int tid = threadIdx.x, wid = tid >> 6, lane = tid & 63;
    float s = 0.f;
    for (int b = tid; b < nb; b += 256) s += part[(size_t)k * nb + b];
    s += __shfl_xor(s, 1);  s += __shfl_xor(s, 2);  s += __shfl_xor(s, 4);
    s += __shfl_xor(s, 8);  s += __shfl_xor(s, 16); s += __shfl_xor(s, 32);
    if (lane == 0) lds[wid] = s;
    __syncthreads();
    if (tid == 0) {
        float tot = lds[0] + lds[1] + lds[2] + lds[3];
        invS[k] = 1.0f / tot;
        lS[k] = __log2f(tot);
    }
}

// K2: recompute dist (same deterministic path), write q (non-temporal), fused loss (log2 domain).
__global__ __launch_bounds__(256, 3) void k2_q_loss(
        const float* __restrict__ embeds, const float* __restrict__ centers,
        const float* __restrict__ invS, const float* __restrict__ lS,
        float* __restrict__ q, float* __restrict__ losspart, int nblocks)
{
    __shared__ bf16x8 blds[8][2][64];
    __shared__ float lds4[4];
    const int tid = threadIdx.x, wid = tid >> 6, lane = tid & 63;
    const int m = lane & 15, g = lane >> 4;

    float cnorm[8];
    stage_centers(centers, blds, cnorm, wid, lane, m, g);

    float invSr[8], lSr[8];
    #pragma unroll
    for (int cb = 0; cb < 8; ++cb) {
        invSr[cb] = invS[cb * 16 + m];
        lSr[cb]   = lS[cb * 16 + m];
    }

    float loss = 0.f;
    const int gwid = blockIdx.x * 4 + wid;
    const int nw = nblocks * 4;

    int t = gwid;
    f32x4 n0, n1, n2, n3;
    if (t < NTILES) {
        const float* src = embeds + (size_t)(t * 16 + m) * DIMS + g * 8;
        n0 = *(const f32x4*)src;       n1 = *(const f32x4*)(src + 4);
        n2 = *(const f32x4*)(src + 32); n3 = *(const f32x4*)(src + 36);
    }
    for (; t < NTILES; t += nw) {
        f32x4 c0 = n0, c1 = n1, c2 = n2, c3 = n3;
        int tn = t + nw;
        if (tn < NTILES) {
            const float* src = embeds + (size_t)(tn * 16 + m) * DIMS + g * 8;
            n0 = *(const f32x4*)src;       n1 = *(const f32x4*)(src + 4);
            n2 = *(const f32x4*)(src + 32); n3 = *(const f32x4*)(src + 36);
        }
        bf16x8 a0, a1;
        float en = 0.f;
        #pragma unroll
        for (int j = 0; j < 4; ++j) {
            float f0 = c0[j], f1 = c1[j], f2 = c2[j], f3 = c3[j];
            en += f0 * f0 + f1 * f1 + f2 * f2 + f3 * f3;
            a0[j] = f2bf(f0); a0[j + 4] = f2bf(f1);
            a1[j] = f2bf(f2); a1[j + 4] = f2bf(f3);
        }
        en += __shfl_xor(en, 16);
        en += __shfl_xor(en, 32);
        float er[4];
        #pragma unroll
        for (int r = 0; r < 4; ++r) er[r] = __shfl(en, g * 4 + r);

        f32x4 acc[8];
        #pragma unroll
        for (int cb = 0; cb < 8; ++cb) {
            bf16x8 b0 = blds[cb][0][lane];
            bf16x8 b1 = blds[cb][1][lane];
            f32x4 a = {0.f, 0.f, 0.f, 0.f};
            a = __builtin_amdgcn_mfma_f32_16x16x32_bf16(a0, b0, a, 0, 0, 0);
            a = __builtin_amdgcn_mfma_f32_16x16x32_bf16(a1, b1, a, 0, 0, 0);
            acc[cb] = a;
        }

        float rs[4] = {0.f, 0.f, 0.f, 0.f};
        #pragma unroll
        for (int cb = 0; cb < 8; ++cb) {
            #pragma unroll
            for (int r = 0; r < 4; ++r) {
                float sq = fmaxf(er[r] + cnorm[cb] - 2.0f * acc[cb][r], 0.f);
                float dist = frcp(1.0f + sq);
                acc[cb][r] = dist;
                rs[r] += dist;
            }
        }
        #pragma unroll
        for (int r = 0; r < 4; ++r) {
            rs[r] += __shfl_xor(rs[r], 1);
            rs[r] += __shfl_xor(rs[r], 2);
            rs[r] += __shfl_xor(rs[r], 4);
            rs[r] += __shfl_xor(rs[r], 8);
            rs[r] = frcp(rs[r]);
        }

        float W[4] = {0.f, 0.f, 0.f, 0.f};
        #pragma unroll
        for (int cb = 0; cb < 8; ++cb) {
            #pragma unroll
            for (int r = 0; r < 4; ++r) {
                float qv = acc[cb][r] * rs[r];
                acc[cb][r] = qv;
                __builtin_nontemporal_store(qv,
                    q + (size_t)(t * 16 + g * 4 + r) * KC + cb * 16 + m);
                W[r] += qv * qv * invSr[cb];
            }
        }
        float iw[4], lw[4];
        #pragma unroll
        for (int r = 0; r < 4; ++r) {
            W[r] += __shfl_xor(W[r], 1);
            W[r] += __shfl_xor(W[r], 2);
            W[r] += __shfl_xor(W[r], 4);
            W[r] += __shfl_xor(W[r], 8);
            iw[r] = frcp(W[r]);
            lw[r] = __log2f(W[r]);
        }
        #pragma unroll
        for (int cb = 0; cb < 8; ++cb) {
            #pragma unroll
            for (int r = 0; r < 4; ++r) {
                float qv = acc[cb][r];
                float w = qv * qv * invSr[cb];
                loss += w * iw[r] * (__log2f(qv) - lSr[cb] - lw[r]);
            }
        }
    }

    loss += __shfl_xor(loss, 1);  loss += __shfl_xor(loss, 2);
    loss += __shfl_xor(loss, 4);  loss += __shfl_xor(loss, 8);
    loss += __shfl_xor(loss, 16); loss += __shfl_xor(loss, 32);
    if (lane == 0) lds4[wid] = loss;
    __syncthreads();
    if (tid == 0) losspart[blockIdx.x] = lds4[0] + lds4[1] + lds4[2] + lds4[3];
}

// K2b: final loss reduce; convert log2 -> ln
__global__ __launch_bounds__(1024) void k2b_final(
        const float* __restrict__ losspart, int nb, float* __restrict__ out)
{
    __shared__ float lds[16];
    const int tid = threadIdx.x;
    float s = 0.f;
    for (int b = tid; b < nb; b += 1024) s += losspart[b];
    s += __shfl_xor(s, 1);  s += __shfl_xor(s, 2);  s += __shfl_xor(s, 4);
    s += __shfl_xor(s, 8);  s += __shfl_xor(s, 16); s += __shfl_xor(s, 32);
    if ((tid & 63) == 0) lds[tid >> 6] = s;
    __syncthreads();
    if (tid == 0) {
        float tot = 0.f;
        #pragma unroll
        for (int i = 0; i < 16; ++i) tot += lds[i];
        out[0] = (float)((double)tot * 0.6931471805599453 /
                         (double)((size_t)NROWS * KC));
    }
}

extern "C" void kernel_launch(void* const* d_in, const int* in_sizes, int n_in,
                              void* d_out, int out_size, void* d_ws, size_t ws_size,
                              hipStream_t stream)
{
    const float* embeds  = (const float*)d_in[0];
    const float* centers = (const float*)d_in[1];
    float* out  = (float*)d_out;
    float* qbuf = out + 1;
    float* ws   = (float*)d_ws;

    int GB1 = 1024, GB2 = 768;
    size_t need = ((size_t)GB1 * 128 + 256 + (size_t)GB2) * sizeof(float);
    if (need > ws_size) { GB1 = 512; GB2 = 512; }

    float* colsum_part = ws;                          // 128 * GB1 (transposed)
    float* invS  = ws + (size_t)GB1 * 128;            // 128
    float* lS    = invS + 128;                        // 128
    float* lpart = lS + 128;                          // GB2

    hipLaunchKernelGGL(k1_colsum, dim3(GB1), dim3(256), 0, stream,
                       embeds, centers, colsum_part, GB1);
    hipLaunchKernelGGL(k1b_reduce, dim3(128), dim3(256), 0, stream,
                       colsum_part, invS, lS, GB1);
    hipLaunchKernelGGL(k2_q_loss, dim3(GB2), dim3(256), 0, stream,
                       embeds, centers, invS, lS, qbuf, lpart, GB2);
    hipLaunchKernelGGL(k2b_final, dim3(1), dim3(1024), 0, stream,
                       lpart, GB2, out);
}

// Round 4
// 146.474 us; speedup vs baseline: 1.1638x; 1.1638x over previous
//
#include <hip/hip_runtime.h>
#include <stdint.h>
#include <stddef.h>

typedef __attribute__((ext_vector_type(8))) short bf16x8;
typedef __attribute__((ext_vector_type(4))) float f32x4;

#define NROWS 400000
#define KC 128
#define DIMS 64
#define NTILES (NROWS / 16)

__device__ __forceinline__ short f2bf(float f) {
    union { float f; uint32_t u; } v; v.f = f;
    uint32_t u = v.u;
    uint32_t r = (u + 0x7FFFu + ((u >> 16) & 1u)) >> 16;  // RNE, finite inputs
    return (short)r;
}

__device__ __forceinline__ float frcp(float x) { return __builtin_amdgcn_rcpf(x); }

// Stage center bf16 fragments into LDS (wave 0), cnorm in regs (norm of center cb*16+m).
__device__ __forceinline__ void stage_centers(
        const float* __restrict__ centers, bf16x8 (*blds)[2][64],
        float* cnorm, int wid, int lane, int m, int g)
{
    #pragma unroll
    for (int cb = 0; cb < 8; ++cb) {
        float cacc = 0.f;
        bf16x8 bfr[2];
        #pragma unroll
        for (int h = 0; h < 2; ++h) {
            const float* src = centers + (size_t)(cb * 16 + m) * DIMS + h * 32 + g * 8;
            f32x4 c0 = *(const f32x4*)src;
            f32x4 c1 = *(const f32x4*)(src + 4);
            bf16x8 b;
            #pragma unroll
            for (int j = 0; j < 4; ++j) {
                float f0 = c0[j], f1 = c1[j];
                cacc += f0 * f0 + f1 * f1;
                b[j]     = f2bf(f0);
                b[j + 4] = f2bf(f1);
            }
            bfr[h] = b;
        }
        cacc += __shfl_xor(cacc, 16);
        cacc += __shfl_xor(cacc, 32);
        cnorm[cb] = cacc;
        if (wid == 0) { blds[cb][0][lane] = bfr[0]; blds[cb][1][lane] = bfr[1]; }
    }
    __syncthreads();
}

// K1: column sums of q. Reads embeds only; partials written TRANSPOSED [k][block].
__global__ __launch_bounds__(256, 4) void k1_colsum(
        const float* __restrict__ embeds, const float* __restrict__ centers,
        float* __restrict__ colsum_part, int nblocks)
{
    __shared__ bf16x8 blds[8][2][64];
    __shared__ float cl[4 * 128];
    const int tid = threadIdx.x, wid = tid >> 6, lane = tid & 63;
    const int m = lane & 15, g = lane >> 4;

    float cnorm[8];
    stage_centers(centers, blds, cnorm, wid, lane, m, g);

    float csum[8];
    #pragma unroll
    for (int cb = 0; cb < 8; ++cb) csum[cb] = 0.f;

    const int gwid = blockIdx.x * 4 + wid;
    const int nw = nblocks * 4;

    int t = gwid;
    f32x4 n0, n1, n2, n3;
    if (t < NTILES) {
        const float* src = embeds + (size_t)(t * 16 + m) * DIMS + g * 8;
        n0 = *(const f32x4*)src;       n1 = *(const f32x4*)(src + 4);
        n2 = *(const f32x4*)(src + 32); n3 = *(const f32x4*)(src + 36);
    }
    for (; t < NTILES; t += nw) {
        f32x4 c0 = n0, c1 = n1, c2 = n2, c3 = n3;
        int tn = t + nw;
        if (tn < NTILES) {
            const float* src = embeds + (size_t)(tn * 16 + m) * DIMS + g * 8;
            n0 = *(const f32x4*)src;       n1 = *(const f32x4*)(src + 4);
            n2 = *(const f32x4*)(src + 32); n3 = *(const f32x4*)(src + 36);
        }
        bf16x8 a0, a1;
        float en = 0.f;
        #pragma unroll
        for (int j = 0; j < 4; ++j) {
            float f0 = c0[j], f1 = c1[j], f2 = c2[j], f3 = c3[j];
            en += f0 * f0 + f1 * f1 + f2 * f2 + f3 * f3;
            a0[j] = f2bf(f0); a0[j + 4] = f2bf(f1);
            a1[j] = f2bf(f2); a1[j + 4] = f2bf(f3);
        }
        en += __shfl_xor(en, 16);
        en += __shfl_xor(en, 32);
        float er[4];
        #pragma unroll
        for (int r = 0; r < 4; ++r) er[r] = __shfl(en, g * 4 + r);

        f32x4 acc[8];
        #pragma unroll
        for (int cb = 0; cb < 8; ++cb) {
            bf16x8 b0 = blds[cb][0][lane];
            bf16x8 b1 = blds[cb][1][lane];
            f32x4 a = {0.f, 0.f, 0.f, 0.f};
            a = __builtin_amdgcn_mfma_f32_16x16x32_bf16(a0, b0, a, 0, 0, 0);
            a = __builtin_amdgcn_mfma_f32_16x16x32_bf16(a1, b1, a, 0, 0, 0);
            acc[cb] = a;
        }

        float rs[4] = {0.f, 0.f, 0.f, 0.f};
        #pragma unroll
        for (int cb = 0; cb < 8; ++cb) {
            #pragma unroll
            for (int r = 0; r < 4; ++r) {
                float sq = fmaxf(er[r] + cnorm[cb] - 2.0f * acc[cb][r], 0.f);
                float dist = frcp(1.0f + sq);
                acc[cb][r] = dist;
                rs[r] += dist;
            }
        }
        #pragma unroll
        for (int r = 0; r < 4; ++r) {
            rs[r] += __shfl_xor(rs[r], 1);
            rs[r] += __shfl_xor(rs[r], 2);
            rs[r] += __shfl_xor(rs[r], 4);
            rs[r] += __shfl_xor(rs[r], 8);
            rs[r] = frcp(rs[r]);
        }
        #pragma unroll
        for (int cb = 0; cb < 8; ++cb) {
            #pragma unroll
            for (int r = 0; r < 4; ++r) csum[cb] += acc[cb][r] * rs[r];
        }
    }

    #pragma unroll
    for (int cb = 0; cb < 8; ++cb) {
        csum[cb] += __shfl_xor(csum[cb], 16);
        csum[cb] += __shfl_xor(csum[cb], 32);
    }
    if (lane < 16) {
        #pragma unroll
        for (int cb = 0; cb < 8; ++cb) cl[wid * 128 + cb * 16 + lane] = csum[cb];
    }
    __syncthreads();
    if (tid < 128) {
        float s = cl[tid] + cl[128 + tid] + cl[256 + tid] + cl[384 + tid];
        colsum_part[(size_t)tid * nblocks + blockIdx.x] = s;   // transposed
    }
}

// K1b: 128 blocks, block k reduces contiguous row k -> invS[k], log2S[k]
__global__ __launch_bounds__(256) void k1b_reduce(
        const float* __restrict__ part, float* __restrict__ invS,
        float* __restrict__ lS, int nb)
{
    __shared__ float lds[4];
    const int k = blockIdx.x;
    const int tid = threadIdx.x, wid = tid >> 6, lane = tid & 63;
    float s = 0.f;
    for (int b = tid; b < nb; b += 256) s += part[(size_t)k * nb + b];
    s += __shfl_xor(s, 1);  s += __shfl_xor(s, 2);  s += __shfl_xor(s, 4);
    s += __shfl_xor(s, 8);  s += __shfl_xor(s, 16); s += __shfl_xor(s, 32);
    if (lane == 0) lds[wid] = s;
    __syncthreads();
    if (tid == 0) {
        float tot = lds[0] + lds[1] + lds[2] + lds[3];
        invS[k] = 1.0f / tot;
        lS[k] = __log2f(tot);
    }
}

// K2: recompute dist (same deterministic path), write q (normal stores -> L2
// write-combining), fused loss (log2 domain).
__global__ __launch_bounds__(256) void k2_q_loss(
        const float* __restrict__ embeds, const float* __restrict__ centers,
        const float* __restrict__ invS, const float* __restrict__ lS,
        float* __restrict__ q, float* __restrict__ losspart, int nblocks)
{
    __shared__ bf16x8 blds[8][2][64];
    __shared__ float lds4[4];
    const int tid = threadIdx.x, wid = tid >> 6, lane = tid & 63;
    const int m = lane & 15, g = lane >> 4;

    float cnorm[8];
    stage_centers(centers, blds, cnorm, wid, lane, m, g);

    float invSr[8], lSr[8];
    #pragma unroll
    for (int cb = 0; cb < 8; ++cb) {
        invSr[cb] = invS[cb * 16 + m];
        lSr[cb]   = lS[cb * 16 + m];
    }

    float loss = 0.f;
    const int gwid = blockIdx.x * 4 + wid;
    const int nw = nblocks * 4;

    int t = gwid;
    f32x4 n0, n1, n2, n3;
    if (t < NTILES) {
        const float* src = embeds + (size_t)(t * 16 + m) * DIMS + g * 8;
        n0 = *(const f32x4*)src;       n1 = *(const f32x4*)(src + 4);
        n2 = *(const f32x4*)(src + 32); n3 = *(const f32x4*)(src + 36);
    }
    for (; t < NTILES; t += nw) {
        f32x4 c0 = n0, c1 = n1, c2 = n2, c3 = n3;
        int tn = t + nw;
        if (tn < NTILES) {
            const float* src = embeds + (size_t)(tn * 16 + m) * DIMS + g * 8;
            n0 = *(const f32x4*)src;       n1 = *(const f32x4*)(src + 4);
            n2 = *(const f32x4*)(src + 32); n3 = *(const f32x4*)(src + 36);
        }
        bf16x8 a0, a1;
        float en = 0.f;
        #pragma unroll
        for (int j = 0; j < 4; ++j) {
            float f0 = c0[j], f1 = c1[j], f2 = c2[j], f3 = c3[j];
            en += f0 * f0 + f1 * f1 + f2 * f2 + f3 * f3;
            a0[j] = f2bf(f0); a0[j + 4] = f2bf(f1);
            a1[j] = f2bf(f2); a1[j + 4] = f2bf(f3);
        }
        en += __shfl_xor(en, 16);
        en += __shfl_xor(en, 32);
        float er[4];
        #pragma unroll
        for (int r = 0; r < 4; ++r) er[r] = __shfl(en, g * 4 + r);

        f32x4 acc[8];
        #pragma unroll
        for (int cb = 0; cb < 8; ++cb) {
            bf16x8 b0 = blds[cb][0][lane];
            bf16x8 b1 = blds[cb][1][lane];
            f32x4 a = {0.f, 0.f, 0.f, 0.f};
            a = __builtin_amdgcn_mfma_f32_16x16x32_bf16(a0, b0, a, 0, 0, 0);
            a = __builtin_amdgcn_mfma_f32_16x16x32_bf16(a1, b1, a, 0, 0, 0);
            acc[cb] = a;
        }

        float rs[4] = {0.f, 0.f, 0.f, 0.f};
        #pragma unroll
        for (int cb = 0; cb < 8; ++cb) {
            #pragma unroll
            for (int r = 0; r < 4; ++r) {
                float sq = fmaxf(er[r] + cnorm[cb] - 2.0f * acc[cb][r], 0.f);
                float dist = frcp(1.0f + sq);
                acc[cb][r] = dist;
                rs[r] += dist;
            }
        }
        #pragma unroll
        for (int r = 0; r < 4; ++r) {
            rs[r] += __shfl_xor(rs[r], 1);
            rs[r] += __shfl_xor(rs[r], 2);
            rs[r] += __shfl_xor(rs[r], 4);
            rs[r] += __shfl_xor(rs[r], 8);
            rs[r] = frcp(rs[r]);
        }

        float W[4] = {0.f, 0.f, 0.f, 0.f};
        #pragma unroll
        for (int cb = 0; cb < 8; ++cb) {
            #pragma unroll
            for (int r = 0; r < 4; ++r) {
                float qv = acc[cb][r] * rs[r];
                acc[cb][r] = qv;
                q[(size_t)(t * 16 + g * 4 + r) * KC + cb * 16 + m] = qv;
                W[r] += qv * qv * invSr[cb];
            }
        }
        float iw[4], lw[4];
        #pragma unroll
        for (int r = 0; r < 4; ++r) {
            W[r] += __shfl_xor(W[r], 1);
            W[r] += __shfl_xor(W[r], 2);
            W[r] += __shfl_xor(W[r], 4);
            W[r] += __shfl_xor(W[r], 8);
            iw[r] = frcp(W[r]);
            lw[r] = __log2f(W[r]);
        }
        #pragma unroll
        for (int cb = 0; cb < 8; ++cb) {
            #pragma unroll
            for (int r = 0; r < 4; ++r) {
                float qv = acc[cb][r];
                float w = qv * qv * invSr[cb];
                loss += w * iw[r] * (__log2f(qv) - lSr[cb] - lw[r]);
            }
        }
    }

    loss += __shfl_xor(loss, 1);  loss += __shfl_xor(loss, 2);
    loss += __shfl_xor(loss, 4);  loss += __shfl_xor(loss, 8);
    loss += __shfl_xor(loss, 16); loss += __shfl_xor(loss, 32);
    if (lane == 0) lds4[wid] = loss;
    __syncthreads();
    if (tid == 0) losspart[blockIdx.x] = lds4[0] + lds4[1] + lds4[2] + lds4[3];
}

// K2b: final loss reduce; convert log2 -> ln
__global__ __launch_bounds__(1024) void k2b_final(
        const float* __restrict__ losspart, int nb, float* __restrict__ out)
{
    __shared__ float lds[16];
    const int tid = threadIdx.x;
    float s = 0.f;
    for (int b = tid; b < nb; b += 1024) s += losspart[b];
    s += __shfl_xor(s, 1);  s += __shfl_xor(s, 2);  s += __shfl_xor(s, 4);
    s += __shfl_xor(s, 8);  s += __shfl_xor(s, 16); s += __shfl_xor(s, 32);
    if ((tid & 63) == 0) lds[tid >> 6] = s;
    __syncthreads();
    if (tid == 0) {
        float tot = 0.f;
        #pragma unroll
        for (int i = 0; i < 16; ++i) tot += lds[i];
        out[0] = (float)((double)tot * 0.6931471805599453 /
                         (double)((size_t)NROWS * KC));
    }
}

extern "C" void kernel_launch(void* const* d_in, const int* in_sizes, int n_in,
                              void* d_out, int out_size, void* d_ws, size_t ws_size,
                              hipStream_t stream)
{
    const float* embeds  = (const float*)d_in[0];
    const float* centers = (const float*)d_in[1];
    float* out  = (float*)d_out;
    float* qbuf = out + 1;
    float* ws   = (float*)d_ws;

    int GB1 = 1024, GB2 = 1024;
    size_t need = ((size_t)GB1 * 128 + 256 + (size_t)GB2) * sizeof(float);
    if (need > ws_size) { GB1 = 512; GB2 = 512; }

    float* colsum_part = ws;                          // 128 * GB1 (transposed)
    float* invS  = ws + (size_t)GB1 * 128;            // 128
    float* lS    = invS + 128;                        // 128
    float* lpart = lS + 128;                          // GB2

    hipLaunchKernelGGL(k1_colsum, dim3(GB1), dim3(256), 0, stream,
                       embeds, centers, colsum_part, GB1);
    hipLaunchKernelGGL(k1b_reduce, dim3(128), dim3(256), 0, stream,
                       colsum_part, invS, lS, GB1);
    hipLaunchKernelGGL(k2_q_loss, dim3(GB2), dim3(256), 0, stream,
                       embeds, centers, invS, lS, qbuf, lpart, GB2);
    hipLaunchKernelGGL(k2b_final, dim3(1), dim3(1024), 0, stream,
                       lpart, GB2, out);
}